// Round 9
// baseline (210.559 us; speedup 1.0000x reference)
//
#include <hip/hip_runtime.h>
#include <cstdint>

// LSTM cell with (diagonal) peephole connections.
//   K1: cast x|hx -> bf16 A [4096][2048]; cast Wih|Whh -> bf16 W' [4096][2048]
//       with gate-interleaved row permutation np = (h>>4)*64 + g*16 + (h&15)
//       (64-wide gate groups; gate g = n-frag j in the epilogue).
//   K2: 256x256 bf16 MFMA GEMM, 512 thr = 8 waves (2M x 4N), wave tile
//       128Mx64N acc[8][4], 16x16x32 MFMA, BK=64, double-buffered 128 KiB LDS.
//   Round-9: r2 skeleton (the only structure of 7 tried that reached 84us)
//   with phases re-cut 4 -> 2 (barriers 9 -> 5/tile). Evidence:
//     - r8 (32x32 shape, same skeleton): HALF the MFMA instructions at a 15%
//       faster pipe was SLOWER (119us) -> the wall is NOT MFMA issue, LDS BW,
//       HBM, or spill. Per-phase fixed cost (barrier rendezvous of 8 waves +
//       lockstep-exposed lgkm latency ~1400cyc/phase vs 154cyc MFMA work)
//       is the only remaining term. This round halves the phase count while
//       freezing everything else (shape, addresses, swizzle, liveness).
//     - r8 also measured 6.29M bank conflicts for the 32x32 read pattern
//       (chunk constant per 32-lane half vs per 16-lane quad) -> 16x16 kept.
//   Per tile: phase ks in {0,1}:
//     read A m-frags 0..7 + B n-frags 0..3 at k-half ks (12 reads; frag peak
//     48 VGPR = r2's proven-clean level; r4-6 showed 64 -> scratch spill)
//     barrier; lgkm(0); sched_barrier (rule #18); setprio(1);
//     32 INDEPENDENT MFMAs (acc[m][n], 1 per chain; r2 had 8 chains x 2);
//     setprio(0); barrier.
//   Boundary: all 8 staging gload_lds for tile kt+2 -> buf[cur] (every region
//   is read in both phases, so regions die only at tile end; burst issue is
//   cheap and HBM latency is hidden across the whole next tile), then
//   vmcnt(8) = kt+1's 8 loads (issued a full tile ago) retired, kt+2's stay
//   in flight (never vmcnt(0) mid-loop); sched_barrier; barrier.
//   Staging safety: stage targets buf[cur] only after the post-phase-1
//   barrier, reached only after every wave's lgkm(0) retired all its reads
//   of buf[cur]. Writes land during tile kt+1 (which reads buf[cur^1]) ✓.
//   XCD-bijective remap kept (FETCH 83->59MB measured). XOR swizzle
//   chunk' = chunk ^ (row&7) on the global source of global_load_lds and on
//   LDS reads: 0 bank conflicts (measured, r2). ds_reads are inline asm
//   (invisible to alias analysis; ordering via barriers + lgkm +
//   sched_barrier). Fused LSTM epilogue, lane-local: gate g = n-frag j.

namespace {

constexpr int H   = 1024;   // hidden
constexpr int K2  = 2048;   // I + H
constexpr int BSZ = 4096;   // batch (M)
constexpr size_t OUT_CY = (size_t)BSZ * H;

typedef __attribute__((ext_vector_type(8))) short bf16x8;
typedef __attribute__((ext_vector_type(4))) float f32x4;
typedef __attribute__((ext_vector_type(8))) unsigned short u16x8;

__device__ __forceinline__ unsigned short f2bf(float f) {
  union { float f; uint32_t u; } v; v.f = f;
  uint32_t u = v.u;
  u += 0x7FFFu + ((u >> 16) & 1u);   // round-to-nearest-even
  return (unsigned short)(u >> 16);
}

__device__ __forceinline__ float sigm(float x) {
  return 1.0f / (1.0f + __expf(-x));
}
__device__ __forceinline__ float tanh_fast(float x) {
  return 1.0f - 2.0f / (1.0f + __expf(2.0f * x));
}

__device__ __forceinline__ void gload_lds16(const void* g, void* l) {
  __builtin_amdgcn_global_load_lds(
      (const __attribute__((address_space(1))) void*)g,
      (__attribute__((address_space(3))) void*)l, 16, 0, 0);
}

// raw ds_read_b128 at LDS byte address; no memory operand -> no compiler
// aliasing ties to global_load_lds destinations. Ordering is explicit.
__device__ __forceinline__ bf16x8 dsr_b128(unsigned addr) {
  bf16x8 r;
  asm volatile("ds_read_b128 %0, %1" : "=v"(r) : "v"(addr));
  return r;
}

}  // namespace

// ---- K1: both casts in one launch -------------------------------------------
__global__ __launch_bounds__(256) void cast_kernel(
    const float* __restrict__ x, const float* __restrict__ hx,
    const float* __restrict__ wih, const float* __restrict__ whh,
    unsigned short* __restrict__ A, unsigned short* __restrict__ W) {
  int b = blockIdx.x;
  bool isW = b >= 4096;
  int t = (isW ? b - 4096 : b) * 256 + threadIdx.x;
  int idx = t * 8;
  int n = idx >> 11;
  int k = idx & 2047;
  const float* s0 = isW ? wih : x;
  const float* s1 = isW ? whh : hx;
  const float* src = (k < H) ? (s0 + (size_t)n * H + k)
                             : (s1 + (size_t)n * H + (k - H));
  float4 v0 = *(const float4*)src;
  float4 v1 = *(const float4*)(src + 4);
  u16x8 o;
  o[0] = f2bf(v0.x); o[1] = f2bf(v0.y); o[2] = f2bf(v0.z); o[3] = f2bf(v0.w);
  o[4] = f2bf(v1.x); o[5] = f2bf(v1.y); o[6] = f2bf(v1.z); o[7] = f2bf(v1.w);
  if (isW) {
    int g = n >> 10, hh = n & 1023;
    int np = ((hh >> 4) << 6) + (g << 4) + (hh & 15);   // 64-wide gate groups
    *(u16x8*)(W + (size_t)np * K2 + k) = o;
  } else {
    *(u16x8*)(A + (size_t)idx) = o;
  }
}

#define LGKM0                                           \
  asm volatile("s_waitcnt lgkmcnt(0)" ::: "memory");    \
  __builtin_amdgcn_sched_barrier(0);

// One k-half phase: 12 reads (A m=0..7, B n=0..3), barrier, 32 indep MFMA.
#define PHASE(BO, KCH)                                                       \
  {                                                                          \
    bf16x8 af[8], bf[4];                                                     \
    _Pragma("unroll") for (int m = 0; m < 8; ++m)                            \
        af[m] = dsr_b128(abase + (BO) + m * 2048 + (KCH));                   \
    _Pragma("unroll") for (int n = 0; n < 4; ++n)                            \
        bf[n] = dsr_b128(bbase + (BO) + n * 2048 + (KCH));                   \
    __builtin_amdgcn_s_barrier();                                            \
    LGKM0;                                                                   \
    __builtin_amdgcn_s_setprio(1);                                           \
    _Pragma("unroll") for (int m = 0; m < 8; ++m)                            \
        _Pragma("unroll") for (int n = 0; n < 4; ++n)                        \
            acc[m][n] = __builtin_amdgcn_mfma_f32_16x16x32_bf16(             \
                af[m], bf[n], acc[m][n], 0, 0, 0);                           \
    __builtin_amdgcn_s_setprio(0);                                           \
    __builtin_amdgcn_s_barrier();                                            \
  }

// One K-tile. BUF is a literal 0/1 at every expansion site.
#define TILE_BODY(KT, BUF)                                                   \
  {                                                                          \
    const unsigned bo = (BUF) * 65536u;                                      \
    PHASE(bo, kch0);                                                         \
    PHASE(bo, kch1);                                                         \
    /* boundary: every wave's reads of buf[BUF] retired (lgkm0) and all   */ \
    /* waves past the trailing barrier -> safe to stage kt+2 into BUF.    */ \
    if ((KT) + 2 < 32) {                                                     \
      stA((KT) + 2, (BUF), 0); stA((KT) + 2, (BUF), 1);                      \
      stA((KT) + 2, (BUF), 2); stA((KT) + 2, (BUF), 3);                      \
      stB((KT) + 2, (BUF), 0); stB((KT) + 2, (BUF), 1);                      \
      stB((KT) + 2, (BUF), 2); stB((KT) + 2, (BUF), 3);                      \
      asm volatile("s_waitcnt vmcnt(8)" ::: "memory"); /* kt+1 landed */     \
    } else {                                                                 \
      asm volatile("s_waitcnt vmcnt(0)" ::: "memory"); /* tail drain */      \
    }                                                                        \
    __builtin_amdgcn_sched_barrier(0);                                       \
    __builtin_amdgcn_s_barrier(); /* tile kt+1 visible to all waves */       \
  }

// ---- K2: fused GEMM + LSTM epilogue -----------------------------------------
// grid = 256 blocks (16x16 logical), block = 512 (8 waves, 2M x 4N)
__global__ __launch_bounds__(512, 2) void lstm_fused_gemm(
    const unsigned short* __restrict__ A,   // [4096][2048] bf16
    const unsigned short* __restrict__ W,   // [4096][2048] bf16, permuted rows
    const float* __restrict__ cx,
    const float* __restrict__ bias_ih, const float* __restrict__ bias_hh,
    const float* __restrict__ Wpi, const float* __restrict__ Wpf,
    float* __restrict__ out) {
  // [buf][ A 256x64 | B 256x64 ] bf16 = 2 * 32768 shorts = 128 KiB
  __shared__ __align__(16) unsigned short lds[2 * 32768];

  const int tid  = threadIdx.x;
  const int lane = tid & 63;
  const int wave = tid >> 6;
  const int wm   = wave >> 2;          // 0..1: M half
  const int wn   = wave & 3;           // 0..3: N quarter

  // XCD-aware bijective remap: linear id b -> XCD b&7 -> 4bx x 8by patch.
  const int b   = blockIdx.y * 16 + blockIdx.x;
  const int xcd = b & 7, bidx = b >> 3;
  const int bx  = (xcd & 3) * 4 + (bidx & 3);
  const int by  = (xcd >> 2) * 8 + (bidx >> 2);
  const int m0 = bx * 256;
  const int w0 = by * 256;             // W' row base

  // staging: thread loads 16B; LDS dest lane-contiguous (global_load_lds rule),
  // XOR swizzle applied to the global source chunk index.
  const int srow   = tid >> 3;                       // 0..63 (row within round)
  const int schunk = ((tid & 7) ^ (srow & 7)) << 3;  // swizzled chunk * 8 hw

  const int col  = lane & 15;
  const int quad = lane >> 4;

  const unsigned short* Asrc = A + (size_t)(m0 + srow) * K2 + schunk;
  const unsigned short* Wsrc = W + (size_t)(w0 + srow) * K2 + schunk;
  const int ldsdst = wave * 512;       // shorts

  f32x4 acc[8][4];
#pragma unroll
  for (int i = 0; i < 8; ++i)
#pragma unroll
    for (int j = 0; j < 4; ++j)
      acc[i][j] = (f32x4){0.f, 0.f, 0.f, 0.f};

  auto stA = [&](int kt, int buf, int p) {
    gload_lds16(Asrc + (size_t)p * 64 * K2 + kt * 64,
                &lds[buf * 32768 + p * 4096 + ldsdst]);
  };
  auto stB = [&](int kt, int buf, int p) {
    gload_lds16(Wsrc + (size_t)p * 64 * K2 + kt * 64,
                &lds[buf * 32768 + 16384 + p * 4096 + ldsdst]);
  };

  // read-side byte addressing: row R at R*128 B, chunk' = chunk ^ (R&7);
  // R&7 == col&7 for all fragment rows (bases are multiples of 16).
  const unsigned lds0 = (unsigned)(size_t)(__attribute__((address_space(3))) char*)lds;
  const unsigned abase = lds0 + (unsigned)((wm * 128 + col) * 128);
  const unsigned bbase = lds0 + 32768u + (unsigned)((wn * 64 + col) * 128);
  const unsigned kch0 = ((quad ^ (col & 7)) << 4);        // ks=0 byte offset
  const unsigned kch1 = (((4 + quad) ^ (col & 7)) << 4);  // ks=1 byte offset

  // ---- prologue: stage tiles 0 (buf0) and 1 (buf1); publish tile 0 ---------
#pragma unroll
  for (int p = 0; p < 4; ++p) stA(0, 0, p);
#pragma unroll
  for (int p = 0; p < 4; ++p) stB(0, 0, p);
#pragma unroll
  for (int p = 0; p < 4; ++p) stA(1, 1, p);
#pragma unroll
  for (int p = 0; p < 4; ++p) stB(1, 1, p);
  asm volatile("s_waitcnt vmcnt(8)" ::: "memory");   // tile0 landed; tile1 in flight
  __builtin_amdgcn_sched_barrier(0);
  __builtin_amdgcn_s_barrier();

  for (int kt = 0; kt < 32; kt += 2) {
    TILE_BODY(kt, 0);
    TILE_BODY(kt + 1, 1);
  }

  // ---- fused LSTM epilogue ----
  // C/D layout: col = lane&15, row = quad*4 + r.  Gate g = N-fragment j.
  // h = by*64 + wn*16 + col  (inverse of np = (h>>4)*64 + g*16 + (h&15)).
  const int h = by * 64 + wn * 16 + col;
  const float bi  = bias_ih[h]         + bias_hh[h];
  const float bf_ = bias_ih[H + h]     + bias_hh[H + h];
  const float bc  = bias_ih[2 * H + h] + bias_hh[2 * H + h];
  const float bo_ = bias_ih[3 * H + h] + bias_hh[3 * H + h];
  const float di = Wpi[(size_t)h * (H + 1)];
  const float df = Wpf[(size_t)h * (H + 1)];
  const int mbase = m0 + wm * 128 + quad * 4;
#pragma unroll
  for (int i = 0; i < 8; ++i) {
#pragma unroll
    for (int r = 0; r < 4; ++r) {
      const int m = mbase + i * 16 + r;
      const float c  = cx[(size_t)m * H + h];
      const float ip = acc[i][0][r] + bi;
      const float fp = acc[i][1][r] + bf_;
      const float cp = acc[i][2][r] + bc;
      const float op = acc[i][3][r] + bo_;
      const float ig = sigm(ip + c * di);
      const float fg = sigm(fp + c * df);
      const float cg = tanh_fast(cp);
      const float cy = fg * c + ig * cg;
      const float og = sigm(op + cy * df);   // reference reuses W_peephole_f
      const float hy = og * tanh_fast(cy);
      out[(size_t)m * H + h] = hy;
      out[OUT_CY + (size_t)m * H + h] = cy;
    }
  }
}

extern "C" void kernel_launch(void* const* d_in, const int* in_sizes, int n_in,
                              void* d_out, int out_size, void* d_ws, size_t ws_size,
                              hipStream_t stream) {
  const float* x   = (const float*)d_in[0];
  const float* hx  = (const float*)d_in[1];
  const float* cx  = (const float*)d_in[2];
  const float* wih = (const float*)d_in[3];
  const float* whh = (const float*)d_in[4];
  const float* bih = (const float*)d_in[5];
  const float* bhh = (const float*)d_in[6];
  const float* wpi = (const float*)d_in[7];
  const float* wpf = (const float*)d_in[8];
  // d_in[9] (W_peephole_o) unused: reference reuses W_peephole_f for outgate.
  float* out = (float*)d_out;

  unsigned short* Abf = (unsigned short*)d_ws;
  unsigned short* Wbf = Abf + (size_t)BSZ * K2;

  cast_kernel<<<8192, 256, 0, stream>>>(x, hx, wih, whh, Abf, Wbf);

  dim3 grid(BSZ / 256, (4 * H) / 256);
  lstm_fused_gemm<<<grid, 512, 0, stream>>>(Abf, Wbf, cx, bih, bhh, wpi, wpf, out);
}